// Round 1
// baseline (544.209 us; speedup 1.0000x reference)
//
#include <hip/hip_runtime.h>
#include <math.h>

#define B_ 16
#define N_ 1024
#define C_ 256

// ---------------------------------------------------------------------------
// Tiled fp32 GEMM: C = alpha * A @ B (BT=0, B[K,N] row-major)
//                  C = alpha * A @ B^T (BT=1, B[N,K] row-major)
// 64x64 tile, BK=16, 256 threads, 4x4 per-thread microtile.
// All problem dims here are multiples of 64/16 -> no bounds checks.
// ---------------------------------------------------------------------------
template <int BT>
__global__ __launch_bounds__(256) void gemm_kernel(
    const float* __restrict__ A, const float* __restrict__ Bm, float* __restrict__ C,
    int M, int N, int K, long sA, long sB, long sC, float alpha)
{
    const int bz = blockIdx.z;
    A += (long)bz * sA;
    Bm += (long)bz * sB;
    C += (long)bz * sC;

    // pad=68 floats: row stride 272 B (16B multiple) -> float4 LDS stores stay aligned
    __shared__ float As[16][68];
    __shared__ float Bs[16][68];

    const int tid = threadIdx.x;
    const int tx = tid & 15;   // 0..15 col group
    const int ty = tid >> 4;   // 0..15 row group
    const int row0 = blockIdx.y * 64;
    const int col0 = blockIdx.x * 64;

    const int lr = tid >> 2;        // 0..63
    const int lk = (tid & 3) * 4;   // 0,4,8,12

    float acc[4][4] = {};

    for (int k0 = 0; k0 < K; k0 += 16) {
        // A tile: rows row0..row0+63, cols k0..k0+15 (transposed store)
        float4 av = *(const float4*)(A + (long)(row0 + lr) * K + (k0 + lk));
        As[lk + 0][lr] = av.x;
        As[lk + 1][lr] = av.y;
        As[lk + 2][lr] = av.z;
        As[lk + 3][lr] = av.w;

        if constexpr (BT) {
            // B[N,K]: tile rows col0..col0+63, cols k0..k0+15 (transposed store)
            float4 bv = *(const float4*)(Bm + (long)(col0 + lr) * K + (k0 + lk));
            Bs[lk + 0][lr] = bv.x;
            Bs[lk + 1][lr] = bv.y;
            Bs[lk + 2][lr] = bv.z;
            Bs[lk + 3][lr] = bv.w;
        } else {
            // B[K,N]: tile rows k0..k0+15, cols col0..col0+63 (direct store)
            int br = tid >> 4;        // 0..15
            int bc = (tid & 15) * 4;  // 0..60
            float4 bv = *(const float4*)(Bm + (long)(k0 + br) * N + (col0 + bc));
            *(float4*)&Bs[br][bc] = bv;
        }
        __syncthreads();

#pragma unroll
        for (int kk = 0; kk < 16; kk++) {
            float a[4], b[4];
#pragma unroll
            for (int i = 0; i < 4; i++) a[i] = As[kk][ty * 4 + i];
#pragma unroll
            for (int j = 0; j < 4; j++) b[j] = Bs[kk][tx * 4 + j];
#pragma unroll
            for (int i = 0; i < 4; i++)
#pragma unroll
                for (int j = 0; j < 4; j++)
                    acc[i][j] = fmaf(a[i], b[j], acc[i][j]);
        }
        __syncthreads();
    }

#pragma unroll
    for (int i = 0; i < 4; i++) {
        float4 o;
        o.x = alpha * acc[i][0];
        o.y = alpha * acc[i][1];
        o.z = alpha * acc[i][2];
        o.w = alpha * acc[i][3];
        *(float4*)(C + (long)(row0 + ty * 4 + i) * N + (col0 + tx * 4)) = o;
    }
}

// ---------------------------------------------------------------------------
// Softmax over the batch axis (axis=0): 16 values per (n,m) cell,
// stride N*N between them. One thread per cell; consecutive threads ->
// consecutive m -> coalesced within each batch slice.
// ---------------------------------------------------------------------------
__global__ __launch_bounds__(256) void softmax_batch(float* __restrict__ S)
{
    const long NN = (long)N_ * N_;
    const long i = (long)blockIdx.x * 256 + threadIdx.x;

    float v[B_];
    float m = -INFINITY;
#pragma unroll
    for (int b = 0; b < B_; b++) {
        v[b] = S[(long)b * NN + i];
        m = fmaxf(m, v[b]);
    }
    float s = 0.f;
#pragma unroll
    for (int b = 0; b < B_; b++) {
        v[b] = __expf(v[b] - m);
        s += v[b];
    }
    const float inv = 1.0f / s;
#pragma unroll
    for (int b = 0; b < B_; b++)
        S[(long)b * NN + i] = v[b] * inv;
}

// ---------------------------------------------------------------------------
// Block-wide sum over 256 threads (wave64 shuffle + 4-slot LDS). Returns the
// same value to all threads. Leading __syncthreads protects `red` reuse.
// ---------------------------------------------------------------------------
__device__ __forceinline__ float block_reduce_sum(float v, float* red)
{
#pragma unroll
    for (int off = 32; off; off >>= 1) v += __shfl_down(v, off, 64);
    __syncthreads();
    if ((threadIdx.x & 63) == 0) red[threadIdx.x >> 6] = v;
    __syncthreads();
    return red[0] + red[1] + red[2] + red[3];
}

// ---------------------------------------------------------------------------
// P kernel: one block per (b,n) row. Recomputes sigma = x[b,n,:] . W_sigma
// (256 MACs, free), then g_j = |n-j| + |sigma|*eps_j, row-normalizes.
// ---------------------------------------------------------------------------
__global__ __launch_bounds__(256) void p_kernel(
    const float* __restrict__ x, const float* __restrict__ Wsig,
    const float* __restrict__ eps, float* __restrict__ P)
{
    __shared__ float red[4];
    const int bn = blockIdx.x;       // b*N + n
    const int n = bn & (N_ - 1);
    const int tid = threadIdx.x;

    const float sig = block_reduce_sum(x[(long)bn * C_ + tid] * Wsig[tid], red);
    const float asig = fabsf(sig);

    const float* erow = eps + (long)bn * N_;
    const float4 e = *(const float4*)(erow + tid * 4);
    const int j0 = tid * 4;
    const float g0 = (float)abs(n - (j0 + 0)) + asig * e.x;
    const float g1 = (float)abs(n - (j0 + 1)) + asig * e.y;
    const float g2 = (float)abs(n - (j0 + 2)) + asig * e.z;
    const float g3 = (float)abs(n - (j0 + 3)) + asig * e.w;

    const float total = block_reduce_sum(g0 + g1 + g2 + g3, red);
    const float inv = 1.0f / total;

    float4 o;
    o.x = g0 * inv;
    o.y = g1 * inv;
    o.z = g2 * inv;
    o.w = g3 * inv;
    *(float4*)(P + (long)bn * N_ + j0) = o;
}

extern "C" void kernel_launch(void* const* d_in, const int* in_sizes, int n_in,
                              void* d_out, int out_size, void* d_ws, size_t ws_size,
                              hipStream_t stream)
{
    const float* x    = (const float*)d_in[0];
    const float* Wq   = (const float*)d_in[1];
    const float* Wk   = (const float*)d_in[2];
    const float* Wv   = (const float*)d_in[3];
    const float* Wsig = (const float*)d_in[4];
    const float* eps  = (const float*)d_in[5];
    float* out = (float*)d_out;

    const long ZN = (long)B_ * N_ * C_;   // 4,194,304
    const long PN = (long)B_ * N_ * N_;   // 16,777,216
    const long NC = (long)N_ * C_;
    const long NN = (long)N_ * N_;

    float* Zp = out;
    float* Pp = out + ZN;       // P region, 16M floats
    float* Sp = out + ZN + PN;  // S region, 16M floats

    // Stage Q/K/V inside the P region (48 MiB of its 64 MiB); the P kernel
    // overwrites it last, after all consumers are done. No d_ws dependence.
    float* Qp = Pp;
    float* Kp = Pp + ZN;
    float* Vp = Pp + 2 * ZN;

    const dim3 blk(256);

    // Q, K, V = x @ W  ([16384,256] @ [256,256])
    gemm_kernel<0><<<dim3(4, 256, 1), blk, 0, stream>>>(x, Wq, Qp, B_ * N_, C_, C_, 0, 0, 0, 1.0f);
    gemm_kernel<0><<<dim3(4, 256, 1), blk, 0, stream>>>(x, Wk, Kp, B_ * N_, C_, C_, 0, 0, 0, 1.0f);
    gemm_kernel<0><<<dim3(4, 256, 1), blk, 0, stream>>>(x, Wv, Vp, B_ * N_, C_, C_, 0, 0, 0, 1.0f);

    // scores = Q @ K^T / sqrt(256), batched over 16 -> into S region
    gemm_kernel<1><<<dim3(16, 16, 16), blk, 0, stream>>>(Qp, Kp, Sp, N_, N_, C_, NC, NC, NN, 0.0625f);

    // softmax over batch axis, in place
    softmax_batch<<<dim3(NN / 256), blk, 0, stream>>>(Sp);

    // Z = S @ V, batched over 16
    gemm_kernel<0><<<dim3(4, 16, 16), blk, 0, stream>>>(Sp, Vp, Zp, N_, C_, N_, NN, NC, NC, 1.0f);

    // P (overwrites the Q/K/V staging region)
    p_kernel<<<dim3(B_ * N_), blk, 0, stream>>>(x, Wsig, eps, Pp);
}

// Round 2
// 306.534 us; speedup vs baseline: 1.7754x; 1.7754x over previous
//
#include <hip/hip_runtime.h>
#include <hip/hip_bf16.h>
#include <math.h>

#define B_ 16
#define N_ 1024
#define C_ 256

typedef unsigned short ushort_t;
typedef __attribute__((ext_vector_type(8))) short short8;   // 8 bf16 = 4 VGPRs
typedef __attribute__((ext_vector_type(4))) float f32x4;

static __device__ __forceinline__ ushort_t f2bf(float f) {
    __hip_bfloat16 h = __float2bfloat16(f);
    return *(ushort_t*)&h;
}

// async global->LDS, 16B per lane; lds base must be wave-uniform (HW adds lane*16)
static __device__ __forceinline__ void async16(const ushort_t* g, ushort_t* l) {
    __builtin_amdgcn_global_load_lds(
        (const __attribute__((address_space(1))) unsigned int*)g,
        (__attribute__((address_space(3))) unsigned int*)l,
        16, 0, 0);
}

// ---------------------------------------------------------------------------
// C[M,N] = alpha * A[M,K] @ B[N,K]^T   (A,B bf16 row-major; C fp32 or bf16)
// 128x128 tile, BK=32, 4 waves (2x2), 16x16x32 MFMA, 4x4 tiles/wave.
// LDS slots XOR-swizzled so frag ds_read_b128 is <=2-way bank aliased (free).
// All dims multiples of 128/32 -> no bounds checks.
// ---------------------------------------------------------------------------
template <int OUT_BF16>
__global__ __launch_bounds__(256) void gemm_nt_bf16(
    const ushort_t* __restrict__ A, const ushort_t* __restrict__ B,
    void* __restrict__ Cp, int M, int N, int K,
    long sA, long sB, long sC, float alpha)
{
    A += (long)blockIdx.z * sA;
    B += (long)blockIdx.z * sB;

    __shared__ ushort_t As[128 * 32];
    __shared__ ushort_t Bs[128 * 32];

    const int tid  = threadIdx.x;
    const int wave = tid >> 6;          // 0..3
    const int lane = tid & 63;
    const int wm   = wave >> 1;         // row half of 128
    const int wn   = wave & 1;          // col half of 128
    const int row0 = blockIdx.y * 128;
    const int col0 = blockIdx.x * 128;

    // ---- staging addresses (per wave: 2 groups of 16 rows for A, 2 for B)
    const int r_grp = lane >> 2;        // 0..15 row within group
    const int c_chk = lane & 3;         // 0..3  16B chunk within 64B row
    const int swz   = c_chk ^ ((r_grp >> 1) & 3);   // swizzled source chunk
    const int ga0 = wave * 2, ga1 = wave * 2 + 1;

    const ushort_t* agp0 = A + (long)(row0 + ga0 * 16 + r_grp) * K + swz * 8;
    const ushort_t* agp1 = A + (long)(row0 + ga1 * 16 + r_grp) * K + swz * 8;
    const ushort_t* bgp0 = B + (long)(col0 + ga0 * 16 + r_grp) * K + swz * 8;
    const ushort_t* bgp1 = B + (long)(col0 + ga1 * 16 + r_grp) * K + swz * 8;
    ushort_t* lA0 = &As[ga0 * 512];
    ushort_t* lA1 = &As[ga1 * 512];
    ushort_t* lB0 = &Bs[ga0 * 512];
    ushort_t* lB1 = &Bs[ga1 * 512];

    // ---- fragment read addressing
    const int lr16 = lane & 15;
    const int q16  = lane >> 4;                       // 0..3
    const int slot = (q16 ^ ((lr16 >> 1) & 3)) * 8;   // swizzled read slot

    f32x4 acc[4][4] = {};

    for (int k0 = 0; k0 < K; k0 += 32) {
        async16(agp0 + k0, lA0);
        async16(agp1 + k0, lA1);
        async16(bgp0 + k0, lB0);
        async16(bgp1 + k0, lB1);
        __syncthreads();   // drains vmcnt (global_load_lds) + lgkm

        short8 av[4], bv[4];
#pragma unroll
        for (int i = 0; i < 4; i++)
            av[i] = *(const short8*)&As[(wm * 64 + i * 16 + lr16) * 32 + slot];
#pragma unroll
        for (int j = 0; j < 4; j++)
            bv[j] = *(const short8*)&Bs[(wn * 64 + j * 16 + lr16) * 32 + slot];

#pragma unroll
        for (int i = 0; i < 4; i++)
#pragma unroll
            for (int j = 0; j < 4; j++)
                acc[i][j] = __builtin_amdgcn_mfma_f32_16x16x32_bf16(
                    av[i], bv[j], acc[i][j], 0, 0, 0);

        __syncthreads();   // protect LDS before next stage
    }

    // ---- epilogue: C/D layout col=lane&15, row=q*4+reg
#pragma unroll
    for (int i = 0; i < 4; i++) {
#pragma unroll
        for (int j = 0; j < 4; j++) {
            const int gr = row0 + wm * 64 + i * 16 + q16 * 4;
            const int gc = col0 + wn * 64 + j * 16 + lr16;
#pragma unroll
            for (int r = 0; r < 4; r++) {
                const float v = alpha * acc[i][j][r];
                if constexpr (OUT_BF16) {
                    ushort_t* C = (ushort_t*)Cp + (long)blockIdx.z * sC;
                    C[(long)(gr + r) * N + gc] = f2bf(v);
                } else {
                    float* C = (float*)Cp + (long)blockIdx.z * sC;
                    C[(long)(gr + r) * N + gc] = v;
                }
            }
        }
    }
}

// ---------------------------------------------------------------------------
// cast x fp32 -> bf16, vectorized x4
// ---------------------------------------------------------------------------
__global__ __launch_bounds__(256) void cast_x_kernel(
    const float* __restrict__ x, ushort_t* __restrict__ xbf)
{
    const long i = ((long)blockIdx.x * 256 + threadIdx.x) * 4;
    const float4 v = *(const float4*)(x + i);
    ushort4 o;
    o.x = f2bf(v.x); o.y = f2bf(v.y); o.z = f2bf(v.z); o.w = f2bf(v.w);
    *(ushort4*)(xbf + i) = o;
}

// ---------------------------------------------------------------------------
// W[256,256] fp32 (z selects q/k/v) -> WbfT[z][256,256] bf16 transposed
// ---------------------------------------------------------------------------
__global__ __launch_bounds__(256) void cast_w_kernel(
    const float* __restrict__ Wq, const float* __restrict__ Wk,
    const float* __restrict__ Wv, ushort_t* __restrict__ WbfT)
{
    __shared__ float t[32][33];
    const float* W = (blockIdx.z == 0) ? Wq : (blockIdx.z == 1) ? Wk : Wv;
    const int n0 = blockIdx.x * 32, k0 = blockIdx.y * 32;
    const int tx = threadIdx.x & 31, ty = threadIdx.x >> 5;   // (32,8)
#pragma unroll
    for (int j = 0; j < 4; j++)
        t[ty + j * 8][tx] = W[(long)(k0 + ty + j * 8) * 256 + n0 + tx];
    __syncthreads();
    ushort_t* o = WbfT + (long)blockIdx.z * 65536;
#pragma unroll
    for (int j = 0; j < 4; j++)
        o[(long)(n0 + ty + j * 8) * 256 + k0 + tx] = f2bf(t[tx][ty + j * 8]);
}

// ---------------------------------------------------------------------------
// Vbf[b][1024,256] -> VbfT[b][256,1024] (bf16 LDS tile transpose)
// ---------------------------------------------------------------------------
__global__ __launch_bounds__(256) void transpose_v_kernel(
    const ushort_t* __restrict__ V, ushort_t* __restrict__ VT)
{
    __shared__ ushort_t t[32][33];
    const long NC = (long)N_ * C_;
    const ushort_t* Vb = V + (long)blockIdx.z * NC;
    ushort_t* Tb = VT + (long)blockIdx.z * NC;
    const int n0 = blockIdx.x * 32, m0 = blockIdx.y * 32;
    const int tx = threadIdx.x & 31, ty = threadIdx.x >> 5;
#pragma unroll
    for (int j = 0; j < 4; j++)
        t[ty + j * 8][tx] = Vb[(long)(m0 + ty + j * 8) * C_ + n0 + tx];
    __syncthreads();
#pragma unroll
    for (int j = 0; j < 4; j++)
        Tb[(long)(n0 + ty + j * 8) * N_ + m0 + tx] = t[tx][ty + j * 8];
}

// ---------------------------------------------------------------------------
// Softmax over batch axis (16 slices, stride N*N); writes fp32 S and bf16 Sbf
// ---------------------------------------------------------------------------
__global__ __launch_bounds__(256) void softmax_batch(
    float* __restrict__ S, ushort_t* __restrict__ Sbf)
{
    const long NN = (long)N_ * N_;
    const long i = (long)blockIdx.x * 256 + threadIdx.x;

    float v[B_];
    float m = -INFINITY;
#pragma unroll
    for (int b = 0; b < B_; b++) {
        v[b] = S[(long)b * NN + i];
        m = fmaxf(m, v[b]);
    }
    float s = 0.f;
#pragma unroll
    for (int b = 0; b < B_; b++) {
        v[b] = __expf(v[b] - m);
        s += v[b];
    }
    const float inv = 1.0f / s;
#pragma unroll
    for (int b = 0; b < B_; b++) {
        const float o = v[b] * inv;
        S[(long)b * NN + i] = o;
        Sbf[(long)b * NN + i] = f2bf(o);
    }
}

// ---------------------------------------------------------------------------
// block reduce + P kernel (unchanged from round 1 — passed)
// ---------------------------------------------------------------------------
__device__ __forceinline__ float block_reduce_sum(float v, float* red)
{
#pragma unroll
    for (int off = 32; off; off >>= 1) v += __shfl_down(v, off, 64);
    __syncthreads();
    if ((threadIdx.x & 63) == 0) red[threadIdx.x >> 6] = v;
    __syncthreads();
    return red[0] + red[1] + red[2] + red[3];
}

__global__ __launch_bounds__(256) void p_kernel(
    const float* __restrict__ x, const float* __restrict__ Wsig,
    const float* __restrict__ eps, float* __restrict__ P)
{
    __shared__ float red[4];
    const int bn = blockIdx.x;
    const int n = bn & (N_ - 1);
    const int tid = threadIdx.x;

    const float sig = block_reduce_sum(x[(long)bn * C_ + tid] * Wsig[tid], red);
    const float asig = fabsf(sig);

    const float* erow = eps + (long)bn * N_;
    const float4 e = *(const float4*)(erow + tid * 4);
    const int j0 = tid * 4;
    const float g0 = (float)abs(n - (j0 + 0)) + asig * e.x;
    const float g1 = (float)abs(n - (j0 + 1)) + asig * e.y;
    const float g2 = (float)abs(n - (j0 + 2)) + asig * e.z;
    const float g3 = (float)abs(n - (j0 + 3)) + asig * e.w;

    const float total = block_reduce_sum(g0 + g1 + g2 + g3, red);
    const float inv = 1.0f / total;

    float4 o;
    o.x = g0 * inv; o.y = g1 * inv; o.z = g2 * inv; o.w = g3 * inv;
    *(float4*)(P + (long)bn * N_ + j0) = o;
}

extern "C" void kernel_launch(void* const* d_in, const int* in_sizes, int n_in,
                              void* d_out, int out_size, void* d_ws, size_t ws_size,
                              hipStream_t stream)
{
    const float* x    = (const float*)d_in[0];
    const float* Wq   = (const float*)d_in[1];
    const float* Wk   = (const float*)d_in[2];
    const float* Wv   = (const float*)d_in[3];
    const float* Wsig = (const float*)d_in[4];
    const float* eps  = (const float*)d_in[5];
    float* out = (float*)d_out;

    const long ZN = (long)B_ * N_ * C_;   // 4,194,304
    const long PN = (long)B_ * N_ * N_;   // 16,777,216
    const long NC = (long)N_ * C_;
    const long NN = (long)N_ * N_;

    float* Zp = out;
    float* Pp = out + ZN;        // 64 MiB region, staged then overwritten last
    float* Sp = out + ZN + PN;

    // bf16 staging inside P region (lifetime-overlapped; see timeline):
    //  [0,8M)B Qbf | [8,16M) Kbf | [16,24M) Vbf | [24,32M) xbf -> VbfT | [32,64M) WbfT -> Sbf
    ushort_t* base = (ushort_t*)Pp;
    ushort_t* Qbf  = base;
    ushort_t* Kbf  = base + ZN;
    ushort_t* Vbf  = base + 2 * ZN;
    ushort_t* xbf  = base + 3 * ZN;   // dead after QKV gemm
    ushort_t* VbfT = base + 3 * ZN;   // born at transpose (after xbf dead)
    ushort_t* WbfT = base + 4 * ZN;   // dead after QKV gemm
    ushort_t* Sbf  = base + 4 * ZN;   // born at softmax (after WbfT dead)

    const dim3 blk(256);

    // casts
    cast_x_kernel<<<dim3((B_ * N_ * C_) / 1024), blk, 0, stream>>>(x, xbf);
    cast_w_kernel<<<dim3(8, 8, 3), blk, 0, stream>>>(Wq, Wk, Wv, WbfT);

    // Q|K|V = xbf @ WbfT^T  -> bf16, one batched launch (z strides both B and C)
    gemm_nt_bf16<1><<<dim3(2, 128, 3), blk, 0, stream>>>(
        xbf, WbfT, Qbf, B_ * N_, C_, C_, 0, 65536, ZN, 1.0f);

    // V -> V^T (bf16) for the Z gemm's B operand
    transpose_v_kernel<<<dim3(8, 32, 16), blk, 0, stream>>>(Vbf, VbfT);

    // scores = Qbf @ Kbf^T / 16 -> S fp32
    gemm_nt_bf16<0><<<dim3(8, 8, 16), blk, 0, stream>>>(
        Qbf, Kbf, Sp, N_, N_, C_, NC, NC, NN, 0.0625f);

    // softmax over batch axis; emits fp32 S (final output) + bf16 Sbf
    softmax_batch<<<dim3(NN / 256), blk, 0, stream>>>(Sp, Sbf);

    // Z = Sbf @ VbfT^T -> fp32
    gemm_nt_bf16<0><<<dim3(2, 8, 16), blk, 0, stream>>>(
        Sbf, VbfT, Zp, N_, C_, N_, NN, NC, NC, 1.0f);

    // P last (overwrites all bf16 staging)
    p_kernel<<<dim3(B_ * N_), blk, 0, stream>>>(x, Wsig, eps, Pp);
}

// Round 3
// 306.532 us; speedup vs baseline: 1.7754x; 1.0000x over previous
//
#include <hip/hip_runtime.h>
#include <hip/hip_bf16.h>
#include <math.h>

#define B_ 16
#define N_ 1024
#define C_ 256

typedef unsigned short ushort_t;
typedef __attribute__((ext_vector_type(8))) short short8;   // 8 bf16 = 4 VGPRs
typedef __attribute__((ext_vector_type(4))) float f32x4;

static __device__ __forceinline__ ushort_t f2bf(float f) {
    __hip_bfloat16 h = __float2bfloat16(f);
    return *(ushort_t*)&h;
}

// async global->LDS, 16B per lane; lds base must be wave-uniform (HW adds lane*16)
static __device__ __forceinline__ void async16(const ushort_t* g, ushort_t* l) {
    __builtin_amdgcn_global_load_lds(
        (const __attribute__((address_space(1))) unsigned int*)g,
        (__attribute__((address_space(3))) unsigned int*)l,
        16, 0, 0);
}

// ---------------------------------------------------------------------------
// C[M,N] = alpha * A[M,K] @ B[N,K]^T   (A,B bf16 row-major; C fp32 or bf16)
// 128x128 tile, BK=32, 4 waves (2x2), 16x16x32 MFMA, 4x4 tiles/wave.
// K-loop LDS XOR-swizzled (<=2-way, free). Epilogue stages acc tiles through
// the same 16KB LDS and emits fully-coalesced float4 / short8 stores.
// All dims multiples of 128/32 -> no bounds checks.
// ---------------------------------------------------------------------------
template <int OUT_BF16>
__global__ __launch_bounds__(256) void gemm_nt_bf16(
    const ushort_t* __restrict__ A, const ushort_t* __restrict__ B,
    void* __restrict__ Cp, int M, int N, int K,
    long sA, long sB, long sC, float alpha)
{
    A += (long)blockIdx.z * sA;
    B += (long)blockIdx.z * sB;

    __shared__ ushort_t sh[2 * 128 * 32];   // As|Bs in K-loop; float[32][128] in epilogue
    ushort_t* As = sh;
    ushort_t* Bs = sh + 128 * 32;
    float* shF = (float*)sh;

    const int tid  = threadIdx.x;
    const int wave = tid >> 6;          // 0..3
    const int lane = tid & 63;
    const int wm   = wave >> 1;         // row half of 128
    const int wn   = wave & 1;          // col half of 128
    const int row0 = blockIdx.y * 128;
    const int col0 = blockIdx.x * 128;

    // ---- staging addresses (per wave: 2 groups of 16 rows for A, 2 for B)
    const int r_grp = lane >> 2;        // 0..15 row within group
    const int c_chk = lane & 3;         // 0..3  16B chunk within 64B row
    const int swz   = c_chk ^ ((r_grp >> 1) & 3);   // swizzled source chunk
    const int ga0 = wave * 2, ga1 = wave * 2 + 1;

    const ushort_t* agp0 = A + (long)(row0 + ga0 * 16 + r_grp) * K + swz * 8;
    const ushort_t* agp1 = A + (long)(row0 + ga1 * 16 + r_grp) * K + swz * 8;
    const ushort_t* bgp0 = B + (long)(col0 + ga0 * 16 + r_grp) * K + swz * 8;
    const ushort_t* bgp1 = B + (long)(col0 + ga1 * 16 + r_grp) * K + swz * 8;
    ushort_t* lA0 = &As[ga0 * 512];
    ushort_t* lA1 = &As[ga1 * 512];
    ushort_t* lB0 = &Bs[ga0 * 512];
    ushort_t* lB1 = &Bs[ga1 * 512];

    // ---- fragment read addressing
    const int lr16 = lane & 15;
    const int q16  = lane >> 4;                       // 0..3
    const int slot = (q16 ^ ((lr16 >> 1) & 3)) * 8;   // swizzled read slot

    f32x4 acc[4][4] = {};

    for (int k0 = 0; k0 < K; k0 += 32) {
        async16(agp0 + k0, lA0);
        async16(agp1 + k0, lA1);
        async16(bgp0 + k0, lB0);
        async16(bgp1 + k0, lB1);
        __syncthreads();   // drains vmcnt (global_load_lds) + lgkm

        short8 av[4], bv[4];
#pragma unroll
        for (int i = 0; i < 4; i++)
            av[i] = *(const short8*)&As[(wm * 64 + i * 16 + lr16) * 32 + slot];
#pragma unroll
        for (int j = 0; j < 4; j++)
            bv[j] = *(const short8*)&Bs[(wn * 64 + j * 16 + lr16) * 32 + slot];

#pragma unroll
        for (int i = 0; i < 4; i++)
#pragma unroll
            for (int j = 0; j < 4; j++)
                acc[i][j] = __builtin_amdgcn_mfma_f32_16x16x32_bf16(
                    av[i], bv[j], acc[i][j], 0, 0, 0);

        __syncthreads();   // protect LDS before next stage (also guards epilogue reuse)
    }

    // ---- epilogue via LDS: 4 passes of 32 rows x 128 cols fp32 (16 KB)
    // acc C/D layout: col=lane&15, row=q16*4+reg
#pragma unroll
    for (int i = 0; i < 4; i++) {
#pragma unroll
        for (int j = 0; j < 4; j++) {
            const int rl = wm * 16 + q16 * 4;         // +r below
            const int cl = wn * 64 + j * 16 + lr16;
#pragma unroll
            for (int r = 0; r < 4; r++) {
                const int rr = rl + r;
                const int xr = ((rr >> 2) & 1) << 4;  // split quads across bank halves
                shF[rr * 128 + (cl ^ xr)] = alpha * acc[i][j][r];
            }
        }
        __syncthreads();

        if constexpr (OUT_BF16) {
            ushort_t* C = (ushort_t*)Cp + (long)blockIdx.z * sC;
#pragma unroll
            for (int v = 0; v < 2; v++) {
                const int idx = v * 256 + tid;        // 0..511 short8-chunks
                const int rl = idx >> 4;              // 32 rows
                const int c8 = idx & 15;              // 16 chunks of 8 elems
                const int xr4 = ((rl >> 2) & 1) << 2; // float4-index XOR
                const int gr = row0 + (rl >> 4) * 64 + i * 16 + (rl & 15);
                const float4 a = ((const float4*)(shF + rl * 128))[(c8 * 2) ^ xr4];
                const float4 b = ((const float4*)(shF + rl * 128))[(c8 * 2 + 1) ^ xr4];
                short8 pk;
                pk[0] = (short)f2bf(a.x); pk[1] = (short)f2bf(a.y);
                pk[2] = (short)f2bf(a.z); pk[3] = (short)f2bf(a.w);
                pk[4] = (short)f2bf(b.x); pk[5] = (short)f2bf(b.y);
                pk[6] = (short)f2bf(b.z); pk[7] = (short)f2bf(b.w);
                *(short8*)(C + (long)gr * N + col0 + c8 * 8) = pk;
            }
        } else {
            float* C = (float*)Cp + (long)blockIdx.z * sC;
#pragma unroll
            for (int v = 0; v < 4; v++) {
                const int idx = v * 256 + tid;        // 0..1023 float4-chunks
                const int rl = idx >> 5;              // 32 rows
                const int c4 = idx & 31;
                const int xr4 = ((rl >> 2) & 1) << 2;
                const int gr = row0 + (rl >> 4) * 64 + i * 16 + (rl & 15);
                const float4 val = ((const float4*)(shF + rl * 128))[c4 ^ xr4];
                *(float4*)(C + (long)gr * N + col0 + c4 * 4) = val;
            }
        }
        __syncthreads();
    }
}

// ---------------------------------------------------------------------------
// cast x fp32 -> bf16, vectorized x4
// ---------------------------------------------------------------------------
__global__ __launch_bounds__(256) void cast_x_kernel(
    const float* __restrict__ x, ushort_t* __restrict__ xbf)
{
    const long i = ((long)blockIdx.x * 256 + threadIdx.x) * 4;
    const float4 v = *(const float4*)(x + i);
    ushort4 o;
    o.x = f2bf(v.x); o.y = f2bf(v.y); o.z = f2bf(v.z); o.w = f2bf(v.w);
    *(ushort4*)(xbf + i) = o;
}

// ---------------------------------------------------------------------------
// W[256,256] fp32 (z selects q/k/v) -> WbfT[z][256,256] bf16 transposed
// ---------------------------------------------------------------------------
__global__ __launch_bounds__(256) void cast_w_kernel(
    const float* __restrict__ Wq, const float* __restrict__ Wk,
    const float* __restrict__ Wv, ushort_t* __restrict__ WbfT)
{
    __shared__ float t[32][33];
    const float* W = (blockIdx.z == 0) ? Wq : (blockIdx.z == 1) ? Wk : Wv;
    const int n0 = blockIdx.x * 32, k0 = blockIdx.y * 32;
    const int tx = threadIdx.x & 31, ty = threadIdx.x >> 5;   // (32,8)
#pragma unroll
    for (int j = 0; j < 4; j++)
        t[ty + j * 8][tx] = W[(long)(k0 + ty + j * 8) * 256 + n0 + tx];
    __syncthreads();
    ushort_t* o = WbfT + (long)blockIdx.z * 65536;
#pragma unroll
    for (int j = 0; j < 4; j++)
        o[(long)(n0 + ty + j * 8) * 256 + k0 + tx] = f2bf(t[tx][ty + j * 8]);
}

// ---------------------------------------------------------------------------
// Vbf[b][1024,256] -> VbfT[b][256,1024] (bf16 LDS tile transpose)
// ---------------------------------------------------------------------------
__global__ __launch_bounds__(256) void transpose_v_kernel(
    const ushort_t* __restrict__ V, ushort_t* __restrict__ VT)
{
    __shared__ ushort_t t[32][33];
    const long NC = (long)N_ * C_;
    const ushort_t* Vb = V + (long)blockIdx.z * NC;
    ushort_t* Tb = VT + (long)blockIdx.z * NC;
    const int n0 = blockIdx.x * 32, m0 = blockIdx.y * 32;
    const int tx = threadIdx.x & 31, ty = threadIdx.x >> 5;
#pragma unroll
    for (int j = 0; j < 4; j++)
        t[ty + j * 8][tx] = Vb[(long)(m0 + ty + j * 8) * C_ + n0 + tx];
    __syncthreads();
#pragma unroll
    for (int j = 0; j < 4; j++)
        Tb[(long)(n0 + ty + j * 8) * N_ + m0 + tx] = t[tx][ty + j * 8];
}

// ---------------------------------------------------------------------------
// Softmax over batch axis (16 slices, stride N*N), 4 cells per thread.
// Writes fp32 S (in place) and bf16 Sbf.
// ---------------------------------------------------------------------------
__global__ __launch_bounds__(256) void softmax_batch(
    float* __restrict__ S, ushort_t* __restrict__ Sbf)
{
    const long NN = (long)N_ * N_;
    const long i4 = ((long)blockIdx.x * 256 + threadIdx.x) * 4;

    float4 v[B_];
    float mx = -INFINITY, my = -INFINITY, mz = -INFINITY, mw = -INFINITY;
#pragma unroll
    for (int b = 0; b < B_; b++) {
        v[b] = *(const float4*)(S + (long)b * NN + i4);
        mx = fmaxf(mx, v[b].x); my = fmaxf(my, v[b].y);
        mz = fmaxf(mz, v[b].z); mw = fmaxf(mw, v[b].w);
    }
    float sx = 0.f, sy = 0.f, sz = 0.f, sw = 0.f;
#pragma unroll
    for (int b = 0; b < B_; b++) {
        v[b].x = __expf(v[b].x - mx); sx += v[b].x;
        v[b].y = __expf(v[b].y - my); sy += v[b].y;
        v[b].z = __expf(v[b].z - mz); sz += v[b].z;
        v[b].w = __expf(v[b].w - mw); sw += v[b].w;
    }
    const float ix = 1.0f / sx, iy = 1.0f / sy, iz = 1.0f / sz, iw = 1.0f / sw;
#pragma unroll
    for (int b = 0; b < B_; b++) {
        float4 o;
        o.x = v[b].x * ix; o.y = v[b].y * iy;
        o.z = v[b].z * iz; o.w = v[b].w * iw;
        *(float4*)(S + (long)b * NN + i4) = o;
        ushort4 ob;
        ob.x = f2bf(o.x); ob.y = f2bf(o.y); ob.z = f2bf(o.z); ob.w = f2bf(o.w);
        *(ushort4*)(Sbf + (long)b * NN + i4) = ob;
    }
}

// ---------------------------------------------------------------------------
// block reduce + P kernel (unchanged — passes)
// ---------------------------------------------------------------------------
__device__ __forceinline__ float block_reduce_sum(float v, float* red)
{
#pragma unroll
    for (int off = 32; off; off >>= 1) v += __shfl_down(v, off, 64);
    __syncthreads();
    if ((threadIdx.x & 63) == 0) red[threadIdx.x >> 6] = v;
    __syncthreads();
    return red[0] + red[1] + red[2] + red[3];
}

__global__ __launch_bounds__(256) void p_kernel(
    const float* __restrict__ x, const float* __restrict__ Wsig,
    const float* __restrict__ eps, float* __restrict__ P)
{
    __shared__ float red[4];
    const int bn = blockIdx.x;
    const int n = bn & (N_ - 1);
    const int tid = threadIdx.x;

    const float sig = block_reduce_sum(x[(long)bn * C_ + tid] * Wsig[tid], red);
    const float asig = fabsf(sig);

    const float* erow = eps + (long)bn * N_;
    const float4 e = *(const float4*)(erow + tid * 4);
    const int j0 = tid * 4;
    const float g0 = (float)abs(n - (j0 + 0)) + asig * e.x;
    const float g1 = (float)abs(n - (j0 + 1)) + asig * e.y;
    const float g2 = (float)abs(n - (j0 + 2)) + asig * e.z;
    const float g3 = (float)abs(n - (j0 + 3)) + asig * e.w;

    const float total = block_reduce_sum(g0 + g1 + g2 + g3, red);
    const float inv = 1.0f / total;

    float4 o;
    o.x = g0 * inv; o.y = g1 * inv; o.z = g2 * inv; o.w = g3 * inv;
    *(float4*)(P + (long)bn * N_ + j0) = o;
}

extern "C" void kernel_launch(void* const* d_in, const int* in_sizes, int n_in,
                              void* d_out, int out_size, void* d_ws, size_t ws_size,
                              hipStream_t stream)
{
    const float* x    = (const float*)d_in[0];
    const float* Wq   = (const float*)d_in[1];
    const float* Wk   = (const float*)d_in[2];
    const float* Wv   = (const float*)d_in[3];
    const float* Wsig = (const float*)d_in[4];
    const float* eps  = (const float*)d_in[5];
    float* out = (float*)d_out;

    const long ZN = (long)B_ * N_ * C_;   // 4,194,304
    const long PN = (long)B_ * N_ * N_;   // 16,777,216
    const long NC = (long)N_ * C_;
    const long NN = (long)N_ * N_;

    float* Zp = out;
    float* Pp = out + ZN;        // 64 MiB region, staged then overwritten last
    float* Sp = out + ZN + PN;

    // bf16 staging inside P region (lifetime-overlapped):
    //  [0,8M)B Qbf | [8,16M) Kbf | [16,24M) Vbf | [24,32M) xbf -> VbfT | [32,64M) WbfT -> Sbf
    ushort_t* base = (ushort_t*)Pp;
    ushort_t* Qbf  = base;
    ushort_t* Kbf  = base + ZN;
    ushort_t* Vbf  = base + 2 * ZN;
    ushort_t* xbf  = base + 3 * ZN;   // dead after QKV gemm
    ushort_t* VbfT = base + 3 * ZN;   // born at transpose (after xbf dead)
    ushort_t* WbfT = base + 4 * ZN;   // dead after QKV gemm
    ushort_t* Sbf  = base + 4 * ZN;   // born at softmax (after WbfT dead)

    const dim3 blk(256);

    // casts
    cast_x_kernel<<<dim3((B_ * N_ * C_) / 1024), blk, 0, stream>>>(x, xbf);
    cast_w_kernel<<<dim3(8, 8, 3), blk, 0, stream>>>(Wq, Wk, Wv, WbfT);

    // Q|K|V = xbf @ WbfT^T  -> bf16, one batched launch (z strides both B and C)
    gemm_nt_bf16<1><<<dim3(2, 128, 3), blk, 0, stream>>>(
        xbf, WbfT, Qbf, B_ * N_, C_, C_, 0, 65536, ZN, 1.0f);

    // V -> V^T (bf16) for the Z gemm's B operand
    transpose_v_kernel<<<dim3(8, 32, 16), blk, 0, stream>>>(Vbf, VbfT);

    // scores = Qbf @ Kbf^T / 16 -> S fp32
    gemm_nt_bf16<0><<<dim3(8, 8, 16), blk, 0, stream>>>(
        Qbf, Kbf, Sp, N_, N_, C_, NC, NC, NN, 0.0625f);

    // softmax over batch axis; emits fp32 S (final output) + bf16 Sbf
    softmax_batch<<<dim3(NN / 1024), blk, 0, stream>>>(Sp, Sbf);

    // Z = Sbf @ VbfT^T -> fp32
    gemm_nt_bf16<0><<<dim3(2, 8, 16), blk, 0, stream>>>(
        Sbf, VbfT, Zp, N_, C_, N_, NN, NC, NC, 1.0f);

    // P last (overwrites all bf16 staging)
    p_kernel<<<dim3(B_ * N_), blk, 0, stream>>>(x, Wsig, eps, Pp);
}